// Round 2
// baseline (1495.415 us; speedup 1.0000x reference)
//
#include <hip/hip_runtime.h>

#define D 64
#define K 1024
#define NTOK (32 * 4096)        // 131072 tokens
#define TPB 256                 // 4 waves per block
#define TOKPB 64                // tokens per block; 4 threads cooperate per token
#define KSPLIT 4                // K-quarters
#define KPT (K / KSPLIT)        // 256 codes per thread
#define TILE 16

#define Q_ELEMS ((size_t)NTOK * D)
#define OH_ELEMS ((size_t)NTOK * K)

__global__ __launch_bounds__(TPB, 6) void vq_kernel(
    const float* __restrict__ X,   // [NTOK, D]
    const float* __restrict__ E,   // [D, K]
    float* __restrict__ qout,      // [NTOK, D]
    float* __restrict__ oneh,      // [NTOK, K]
    float* __restrict__ idxout)    // [NTOK]
{
    __shared__ float e2s[K];
    __shared__ float bd[TPB];
    __shared__ int   bi[TPB];
    __shared__ int   idxs[TOKPB];

    const int tid  = threadIdx.x;
    const int tl   = tid & (TOKPB - 1);   // local token 0..63
    const int sub  = tid >> 6;            // K-quarter 0..3 (wave-uniform)
    const int tok  = blockIdx.x * TOKPB + tl;

    // --- ||e_k||^2 into LDS (same FMA order as R1: d ascending) ---
    for (int k = tid; k < K; k += TPB) {
        float s = 0.f;
        #pragma unroll
        for (int d = 0; d < D; ++d) {
            float v = E[d * K + k];
            s = fmaf(v, v, s);
        }
        e2s[k] = s;
    }
    __syncthreads();

    // --- token into registers (16 x float4); all 4 quarters load same token ---
    float x[D];
    {
        const float* xp = X + (size_t)tok * D;
        #pragma unroll
        for (int j = 0; j < D / 4; ++j) {
            float4 v = *reinterpret_cast<const float4*>(xp + 4 * j);
            x[4 * j + 0] = v.x; x[4 * j + 1] = v.y;
            x[4 * j + 2] = v.z; x[4 * j + 3] = v.w;
        }
    }

    // --- partial argmin over this thread's 256 codes ---
    const int kbase = sub * KPT;
    float best = 3.4e38f;
    int   bidx = 0;
    for (int t0 = kbase; t0 < kbase + KPT; t0 += TILE) {
        float acc[TILE];
        #pragma unroll
        for (int j = 0; j < TILE; ++j) acc[j] = 0.f;

        #pragma unroll
        for (int d = 0; d < D; ++d) {
            const float* ep = E + d * K + t0;
            #pragma unroll
            for (int j = 0; j < TILE; ++j)
                acc[j] = fmaf(x[d], ep[j], acc[j]);
        }

        #pragma unroll
        for (int j = 0; j < TILE; ++j) {
            float dist = fmaf(-2.f, acc[j], e2s[t0 + j]);
            if (dist < best) { best = dist; bidx = t0 + j; }
        }
    }

    bd[tid] = best;
    bi[tid] = bidx;
    __syncthreads();

    // --- reduce 4 quarters per token (quarter-ascending, strict < keeps lowest idx) ---
    if (sub == 0) {
        float fb = bd[tl];
        int   fi = bi[tl];
        #pragma unroll
        for (int q = 1; q < KSPLIT; ++q) {
            float db = bd[q * TOKPB + tl];
            int   di = bi[q * TOKPB + tl];
            if (db < fb) { fb = db; fi = di; }
        }
        idxs[tl] = fi;

        // gather quantized column; STE: x + (q - x), same expr as reference
        float q[D];
        const float* ec = E + fi;
        #pragma unroll
        for (int d = 0; d < D; ++d) q[d] = ec[d * K];

        float* qp = qout + (size_t)tok * D;
        #pragma unroll
        for (int j = 0; j < D / 4; ++j) {
            float4 v;
            v.x = x[4 * j + 0] + (q[4 * j + 0] - x[4 * j + 0]);
            v.y = x[4 * j + 1] + (q[4 * j + 1] - x[4 * j + 1]);
            v.z = x[4 * j + 2] + (q[4 * j + 2] - x[4 * j + 2]);
            v.w = x[4 * j + 3] + (q[4 * j + 3] - x[4 * j + 3]);
            *reinterpret_cast<float4*>(qp + 4 * j) = v;
        }

        idxout[tok] = (float)fi;
    }
    __syncthreads();

    // --- one-hot: 64 rows x 1024, coalesced float4 stores ---
    {
        float4* base = reinterpret_cast<float4*>(oneh + (size_t)blockIdx.x * TOKPB * K);
        const int total = TOKPB * K / 4;      // 16384 float4 per block
        for (int i = tid; i < total; i += TPB) {
            int row = i >> 8;                 // 256 float4 per row
            int c4  = (i & 255) * 4;
            int id  = idxs[row];
            float4 v;
            v.x = (id == c4 + 0) ? 1.f : 0.f;
            v.y = (id == c4 + 1) ? 1.f : 0.f;
            v.z = (id == c4 + 2) ? 1.f : 0.f;
            v.w = (id == c4 + 3) ? 1.f : 0.f;
            base[i] = v;
        }
    }
}

extern "C" void kernel_launch(void* const* d_in, const int* in_sizes, int n_in,
                              void* d_out, int out_size, void* d_ws, size_t ws_size,
                              hipStream_t stream) {
    const float* X = (const float*)d_in[0];
    const float* E = (const float*)d_in[1];

    float* qout   = (float*)d_out;
    float* oneh   = qout + Q_ELEMS;
    float* idxout = oneh + OH_ELEMS;

    const int grid = NTOK / TOKPB;  // 2048 blocks
    vq_kernel<<<grid, TPB, 0, stream>>>(X, E, qout, oneh, idxout);
}

// Round 3
// 1014.507 us; speedup vs baseline: 1.4740x; 1.4740x over previous
//
#include <hip/hip_runtime.h>

#define D 64
#define K 1024
#define NTOK (32 * 4096)        // 131072 tokens
#define TPB 256                 // 4 waves per block
#define TOKPB 64                // tokens per block; 4 threads cooperate per token
#define KSPLIT 4                // K-quarters
#define KPT (K / KSPLIT)        // 256 codes per thread
#define TILE 16

#define Q_ELEMS ((size_t)NTOK * D)
#define OH_ELEMS ((size_t)NTOK * K)

// launch_bounds(,2): 128-VGPR cap — R2's (,6) forced a 42-reg cap and spilled
// x[64] to scratch (VGPR=40, +250MB scratch traffic, 3x slowdown).
__global__ __launch_bounds__(TPB, 2) void vq_kernel(
    const float* __restrict__ X,   // [NTOK, D]
    const float* __restrict__ E,   // [D, K]
    float* __restrict__ qout,      // [NTOK, D]
    float* __restrict__ oneh,      // [NTOK, K]
    float* __restrict__ idxout)    // [NTOK]
{
    __shared__ float e2s[K];
    __shared__ float bd[TPB];
    __shared__ int   bi[TPB];
    __shared__ int   idxs[TOKPB];

    const int tid  = threadIdx.x;
    const int tl   = tid & (TOKPB - 1);   // local token 0..63 (= lane)
    const int sub  = tid >> 6;            // K-quarter 0..3 (wave-uniform)
    const int tok  = blockIdx.x * TOKPB + tl;

    // --- ||e_k||^2 into LDS (same FMA order as R1: d ascending) ---
    for (int k = tid; k < K; k += TPB) {
        float s = 0.f;
        #pragma unroll
        for (int d = 0; d < D; ++d) {
            float v = E[d * K + k];
            s = fmaf(v, v, s);
        }
        e2s[k] = s;
    }
    __syncthreads();

    // --- token into registers (16 x float4); all 4 quarters load same token ---
    float x[D];
    {
        const float* xp = X + (size_t)tok * D;
        #pragma unroll
        for (int j = 0; j < D / 4; ++j) {
            float4 v = *reinterpret_cast<const float4*>(xp + 4 * j);
            x[4 * j + 0] = v.x; x[4 * j + 1] = v.y;
            x[4 * j + 2] = v.z; x[4 * j + 3] = v.w;
        }
    }

    // --- partial argmin over this thread's 256 codes ---
    const int kbase = sub * KPT;
    float best = 3.4e38f;
    int   bidx = 0;
    for (int t0 = kbase; t0 < kbase + KPT; t0 += TILE) {
        float acc[TILE];
        #pragma unroll
        for (int j = 0; j < TILE; ++j) acc[j] = 0.f;

        // E address is wave-uniform (sub,d,t0 only) -> scalar SMEM loads
        #pragma unroll
        for (int d = 0; d < D; ++d) {
            const float* ep = E + d * K + t0;
            #pragma unroll
            for (int j = 0; j < TILE; ++j)
                acc[j] = fmaf(x[d], ep[j], acc[j]);
        }

        #pragma unroll
        for (int j = 0; j < TILE; ++j) {
            float dist = fmaf(-2.f, acc[j], e2s[t0 + j]);
            if (dist < best) { best = dist; bidx = t0 + j; }
        }
    }

    bd[tid] = best;
    bi[tid] = bidx;
    __syncthreads();

    // --- reduce 4 quarters per token (quarter-ascending, strict < keeps lowest idx) ---
    if (sub == 0) {
        float fb = bd[tl];
        int   fi = bi[tl];
        #pragma unroll
        for (int q = 1; q < KSPLIT; ++q) {
            float db = bd[q * TOKPB + tl];
            int   di = bi[q * TOKPB + tl];
            if (db < fb) { fb = db; fi = di; }
        }
        idxs[tl] = fi;

        // gather quantized column; STE: x + (q - x), same expr as reference
        float q[D];
        const float* ec = E + fi;
        #pragma unroll
        for (int d = 0; d < D; ++d) q[d] = ec[d * K];

        float* qp = qout + (size_t)tok * D;
        #pragma unroll
        for (int j = 0; j < D / 4; ++j) {
            float4 v;
            v.x = x[4 * j + 0] + (q[4 * j + 0] - x[4 * j + 0]);
            v.y = x[4 * j + 1] + (q[4 * j + 1] - x[4 * j + 1]);
            v.z = x[4 * j + 2] + (q[4 * j + 2] - x[4 * j + 2]);
            v.w = x[4 * j + 3] + (q[4 * j + 3] - x[4 * j + 3]);
            *reinterpret_cast<float4*>(qp + 4 * j) = v;
        }

        idxout[tok] = (float)fi;
    }
    __syncthreads();

    // --- one-hot: 64 rows x 1024, coalesced float4 stores ---
    {
        float4* base = reinterpret_cast<float4*>(oneh + (size_t)blockIdx.x * TOKPB * K);
        const int total = TOKPB * K / 4;      // 16384 float4 per block
        for (int i = tid; i < total; i += TPB) {
            int row = i >> 8;                 // 256 float4 per row
            int c4  = (i & 255) * 4;
            int id  = idxs[row];
            float4 v;
            v.x = (id == c4 + 0) ? 1.f : 0.f;
            v.y = (id == c4 + 1) ? 1.f : 0.f;
            v.z = (id == c4 + 2) ? 1.f : 0.f;
            v.w = (id == c4 + 3) ? 1.f : 0.f;
            base[i] = v;
        }
    }
}

extern "C" void kernel_launch(void* const* d_in, const int* in_sizes, int n_in,
                              void* d_out, int out_size, void* d_ws, size_t ws_size,
                              hipStream_t stream) {
    const float* X = (const float*)d_in[0];
    const float* E = (const float*)d_in[1];

    float* qout   = (float*)d_out;
    float* oneh   = qout + Q_ELEMS;
    float* idxout = oneh + OH_ELEMS;

    const int grid = NTOK / TOKPB;  // 2048 blocks
    vq_kernel<<<grid, TPB, 0, stream>>>(X, E, qout, oneh, idxout);
}

// Round 4
// 479.666 us; speedup vs baseline: 3.1176x; 2.1150x over previous
//
#include <hip/hip_runtime.h>

#define D 64
#define K 1024
#define NTOK (32 * 4096)        // 131072 tokens
#define TPB 64                  // 1 wave per block
#define TOKPB 64                // tokens per block = threads per block
#define TILE 32                 // codes per inner tile (2x s_load_dwordx16 per d-row)

#define Q_ELEMS ((size_t)NTOK * D)
#define OH_ELEMS ((size_t)NTOK * K)

// kernel0: ||e_k||^2 -> d_ws[k]. Same FMA chain as before (d ascending).
__global__ void e2_kernel(const float* __restrict__ E, float* __restrict__ e2g) {
    int k = blockIdx.x * 256 + threadIdx.x;
    float s = 0.f;
    #pragma unroll
    for (int d = 0; d < D; ++d) {
        float v = E[d * K + k];
        s = fmaf(v, v, s);
    }
    e2g[k] = s;
}

__global__ __launch_bounds__(TPB, 4) void vq_kernel(
    const float* __restrict__ X,    // [NTOK, D]
    const float* __restrict__ E,    // [D, K]
    const float* __restrict__ e2g,  // [K]
    float* __restrict__ qout,       // [NTOK, D]
    float* __restrict__ oneh,       // [NTOK, K]
    float* __restrict__ idxout)     // [NTOK]
{
    __shared__ int idxs[TOKPB];

    const int tid = threadIdx.x;
    const int tok = blockIdx.x * TOKPB + tid;

    // --- token into registers (16 x float4) ---
    float x[D];
    {
        const float* xp = X + (size_t)tok * D;
        #pragma unroll
        for (int j = 0; j < D / 4; ++j) {
            float4 v = *reinterpret_cast<const float4*>(xp + 4 * j);
            x[4 * j + 0] = v.x; x[4 * j + 1] = v.y;
            x[4 * j + 2] = v.z; x[4 * j + 3] = v.w;
        }
    }

    // --- full-K ascending argmin; per-code math identical to R1 ---
    float best = 3.4e38f;
    int   bidx = 0;
    for (int t0 = 0; t0 < K; t0 += TILE) {
        float acc[TILE];
        #pragma unroll
        for (int j = 0; j < TILE; ++j) acc[j] = 0.f;

        // E addresses wave-uniform -> scalar (SMEM) loads, broadcast to lanes
        #pragma unroll
        for (int d = 0; d < D; ++d) {
            const float* ep = E + d * K + t0;
            #pragma unroll
            for (int j = 0; j < TILE; ++j)
                acc[j] = fmaf(x[d], ep[j], acc[j]);
        }

        const float* e2p = e2g + t0;   // uniform -> s_load
        #pragma unroll
        for (int j = 0; j < TILE; ++j) {
            float dist = fmaf(-2.f, acc[j], e2p[j]);
            if (dist < best) { best = dist; bidx = t0 + j; }  // strict <: lowest idx wins
        }
    }

    idxs[tid] = bidx;

    // --- quantized: gather E[:, bidx]; STE x + (q - x) (same expr as reference) ---
    {
        float q[D];
        const float* ec = E + bidx;
        #pragma unroll
        for (int d = 0; d < D; ++d) q[d] = ec[d * K];

        float* qp = qout + (size_t)tok * D;
        #pragma unroll
        for (int j = 0; j < D / 4; ++j) {
            float4 v;
            v.x = x[4 * j + 0] + (q[4 * j + 0] - x[4 * j + 0]);
            v.y = x[4 * j + 1] + (q[4 * j + 1] - x[4 * j + 1]);
            v.z = x[4 * j + 2] + (q[4 * j + 2] - x[4 * j + 2]);
            v.w = x[4 * j + 3] + (q[4 * j + 3] - x[4 * j + 3]);
            *reinterpret_cast<float4*>(qp + 4 * j) = v;
        }

        idxout[tok] = (float)bidx;
    }

    __syncthreads();  // idxs[] visible across the wave's LDS view

    // --- one-hot: 64 rows x 1024, coalesced float4 stores (1KB per wave-instr) ---
    {
        float4* base = reinterpret_cast<float4*>(oneh + (size_t)blockIdx.x * TOKPB * K);
        const int total = TOKPB * K / 4;       // 16384 float4 per block
        for (int i = tid; i < total; i += TPB) {
            int row = i >> 8;                  // 256 float4 per row
            int c4  = (i & 255) * 4;
            int id  = idxs[row];
            float4 v;
            v.x = (id == c4 + 0) ? 1.f : 0.f;
            v.y = (id == c4 + 1) ? 1.f : 0.f;
            v.z = (id == c4 + 2) ? 1.f : 0.f;
            v.w = (id == c4 + 3) ? 1.f : 0.f;
            base[i] = v;
        }
    }
}

extern "C" void kernel_launch(void* const* d_in, const int* in_sizes, int n_in,
                              void* d_out, int out_size, void* d_ws, size_t ws_size,
                              hipStream_t stream) {
    const float* X = (const float*)d_in[0];
    const float* E = (const float*)d_in[1];

    float* qout   = (float*)d_out;
    float* oneh   = qout + Q_ELEMS;
    float* idxout = oneh + OH_ELEMS;
    float* e2g    = (float*)d_ws;   // 4 KB scratch for ||e||^2

    e2_kernel<<<K / 256, 256, 0, stream>>>(E, e2g);
    vq_kernel<<<NTOK / TOKPB, TPB, 0, stream>>>(X, E, e2g, qout, oneh, idxout);
}